// Round 1
// baseline (2222330.664 us; speedup 1.0000x reference)
//
#include <hip/hip_runtime.h>
#include <hip/hip_bf16.h>

// NeuralKalmanFilter: sequential scan over SEQ=4096 steps, 20 inference iters each.
// Key algebra: Wout^T(x - Wout fz) = B[:,t] - G @ fz  with G = Wout^T Wout (precomputed),
// so each inference iteration is ONE 2048x2048 matvec. Drive matvec (Wr) shares the
// phase-0 broadcast. => 4096*20 = 81920 sequential phases.
// Scan runs as a cooperative persistent kernel: 256 blocks (one per CU), each owns 8 rows
// of z; weights (G,Wr slices) live in VGPRs (64 regs/thread, bf16); per phase only the
// 4KB fz vector is broadcast via agent-scope atomics + per-block flags.

#define SEQL 4096
#define NLAT 2048
#define NOBS 1024
#define NCTL 512

typedef unsigned short u16;
typedef unsigned int   u32;
typedef unsigned long long u64;

__device__ __forceinline__ float bfl(u32 u)  { return __uint_as_float(u << 16); }
__device__ __forceinline__ float bfh(u32 u)  { return __uint_as_float(u & 0xffff0000u); }
__device__ __forceinline__ float bf2f(u16 s) { return __uint_as_float(((u32)s) << 16); }
__device__ __forceinline__ u16 f2bf(float f) {            // round-to-nearest-even bf16
  u32 x = __float_as_uint(f);
  return (u16)((x + 0x7fffu + ((x >> 16) & 1u)) >> 16);
}

// ---------------- elementwise converts ----------------
__global__ void k_f2b(const float* __restrict__ in, u16* __restrict__ out, int n) {
  int i = blockIdx.x * 256 + threadIdx.x;
  if (i < n) out[i] = f2bf(in[i]);
}
__global__ void k_tanh2b(const float* __restrict__ in, u16* __restrict__ out, int n) {
  int i = blockIdx.x * 256 + threadIdx.x;
  if (i < n) out[i] = f2bf(tanhf(in[i]));
}
// out[c*R + r] = bf16(in[r*C + c])   (build Wout^T)
__global__ void k_tr2b(const float* __restrict__ in, u16* __restrict__ out, int R, int C) {
  int i = blockIdx.x * 256 + threadIdx.x;
  if (i < R * C) {
    int r = i / C, c = i % C;
    out[(size_t)c * R + r] = f2bf(in[i]);
  }
}

// ---------------- simple LDS-tiled bf16 GEMM (fp32 acc), 64x64 tile ----------------
// C = A(MxK) @ B(KxN), all row-major. Writes fp32 (Cf) or bf16 (Cb); pass the other null.
__global__ __launch_bounds__(256) void gemm_bf16(
    const u16* __restrict__ A, const u16* __restrict__ B,
    float* __restrict__ Cf, u16* __restrict__ Cb, int M, int N, int K)
{
  __shared__ float As[32][68];   // [k][m], +4 pad keeps float4 reads 16B-aligned
  __shared__ float Bs[32][68];   // [k][n]
  const int tid = threadIdx.x;
  const int colBase = blockIdx.x * 64, rowBase = blockIdx.y * 64;
  const int tx = tid & 15, ty = tid >> 4;
  const int ar = tid >> 2, ak = (tid & 3) * 8;   // A: row ar, k = ak..ak+7
  const int bk = tid >> 3, bc = (tid & 7) * 8;   // B: k bk, col bc..bc+7
  const u16* Ap = A + (size_t)(rowBase + ar) * K + ak;
  const u16* Bp = B + (size_t)bk * N + colBase + bc;
  float acc[4][4] = {};

  for (int k0 = 0; k0 < K; k0 += 32) {
    uint4 a = *(const uint4*)(Ap + k0);
    uint4 b = *(const uint4*)(Bp + (size_t)k0 * N);
    As[ak + 0][ar] = bfl(a.x); As[ak + 1][ar] = bfh(a.x);
    As[ak + 2][ar] = bfl(a.y); As[ak + 3][ar] = bfh(a.y);
    As[ak + 4][ar] = bfl(a.z); As[ak + 5][ar] = bfh(a.z);
    As[ak + 6][ar] = bfl(a.w); As[ak + 7][ar] = bfh(a.w);
    Bs[bk][bc + 0] = bfl(b.x); Bs[bk][bc + 1] = bfh(b.x);
    Bs[bk][bc + 2] = bfl(b.y); Bs[bk][bc + 3] = bfh(b.y);
    Bs[bk][bc + 4] = bfl(b.z); Bs[bk][bc + 5] = bfh(b.z);
    Bs[bk][bc + 6] = bfl(b.w); Bs[bk][bc + 7] = bfh(b.w);
    __syncthreads();
#pragma unroll
    for (int kk = 0; kk < 32; kk++) {
      float4 av = *(const float4*)&As[kk][ty * 4];
      float4 bv = *(const float4*)&Bs[kk][tx * 4];
      float a4[4] = {av.x, av.y, av.z, av.w};
      float b4[4] = {bv.x, bv.y, bv.z, bv.w};
#pragma unroll
      for (int i = 0; i < 4; i++)
#pragma unroll
        for (int q = 0; q < 4; q++)
          acc[i][q] = fmaf(a4[i], b4[q], acc[i][q]);
    }
    __syncthreads();
  }

  if (Cf) {
#pragma unroll
    for (int i = 0; i < 4; i++) {
      float4 v = make_float4(acc[i][0], acc[i][1], acc[i][2], acc[i][3]);
      *(float4*)&Cf[(size_t)(rowBase + ty * 4 + i) * N + colBase + tx * 4] = v;
    }
  } else {
#pragma unroll
    for (int i = 0; i < 4; i++) {
      u64 pk = (u64)f2bf(acc[i][0]) | ((u64)f2bf(acc[i][1]) << 16) |
               ((u64)f2bf(acc[i][2]) << 32) | ((u64)f2bf(acc[i][3]) << 48);
      *(u64*)&Cb[(size_t)(rowBase + ty * 4 + i) * N + colBase + tx * 4] = pk;
    }
  }
}

// ---------------- the sequential scan (cooperative, 256 blocks x 256 threads) ----------
__global__ void __launch_bounds__(256, 1)
scan_kernel(const u16* __restrict__ G,      // 2048x2048 bf16  (Wout^T Wout)
            const u16* __restrict__ Wr,     // 2048x2048 bf16
            const u16* __restrict__ Bmat,   // 2048x4096 bf16  (Wout^T @ inputs)
            const u16* __restrict__ Cin,    // 2048x4096 bf16  (Win @ tanh(controls))
            float* __restrict__ zs,         // 2048x4096 f32 out
            u16* __restrict__ td,           // 2048x4096 bf16 out: tanh(drive)
            u32* __restrict__ flags,        // 256, zeroed before launch
            u64* __restrict__ fzbuf,        // 2 parities x 512 u64 (2048 bf16 each)
            const int* __restrict__ itp, const float* __restrict__ lrp)
{
  __shared__ __align__(16) float fzLDS[NLAT];   // current fz, fp32-expanded
  __shared__ float corrLDS[8], wrLDS[8];
  __shared__ u16 fzpack[8];
  __shared__ int sAbort;

  const int tid = threadIdx.x, bid = blockIdx.x;
  const int lane = tid & 63, wave = tid >> 6;
  const int row_local = wave * 2 + (lane >> 5);    // 0..7
  const int chunk = lane & 31;                     // 0..31
  const int row = bid * 8 + row_local;
  const int c0 = chunk * 64;

  const int niters = *itp;       // 20
  const float lr = *lrp;         // 0.05

  // Per-thread weight slice: 64 bf16 of G[row, c0..c0+63] and Wr[row, ...] in VGPRs.
  u32 wG[32], wW[32];
  {
    const u32* gp = (const u32*)(G  + (size_t)row * NLAT + c0);
    const u32* wp = (const u32*)(Wr + (size_t)row * NLAT + c0);
#pragma unroll
    for (int i = 0; i < 32; i++) { wG[i] = gp[i]; wW[i] = wp[i]; }
  }
  for (int i = tid; i < NLAT; i += 256) fzLDS[i] = 0.f;   // z0 = 0 -> fz = 0
  if (tid == 0) sAbort = 0;
  float z = 0.f, fz = 0.f, drive = 0.f, bv = 0.f;          // valid for tid < 8
  __syncthreads();

  u32 p = 0;
  for (int t = 0; t < SEQL; t++) {
    for (int j = 0; j < niters; j++) {
      p++;
      float cv = 0.f;
      if (j == 0 && tid < 8) {      // per-step column loads (prefetched early)
        bv = bf2f(Bmat[(size_t)(bid * 8 + tid) * SEQL + t]);
        cv = bf2f(Cin [(size_t)(bid * 8 + tid) * SEQL + t]);
      }

      // ---- matvec: accG = G[row,:] @ fz ; accW = Wr[row,:] @ fz (needed only j==0) ----
      float accG = 0.f, accW = 0.f;
      const float4* f4 = (const float4*)(fzLDS + c0);
#pragma unroll
      for (int i = 0; i < 16; i++) {
        float4 v = f4[i];
        u32 wa = wG[2 * i], wb = wG[2 * i + 1];
        accG = fmaf(bfl(wa), v.x, accG);
        accG = fmaf(bfh(wa), v.y, accG);
        accG = fmaf(bfl(wb), v.z, accG);
        accG = fmaf(bfh(wb), v.w, accG);
        u32 xa = wW[2 * i], xb = wW[2 * i + 1];
        accW = fmaf(bfl(xa), v.x, accW);
        accW = fmaf(bfh(xa), v.y, accW);
        accW = fmaf(bfl(xb), v.z, accW);
        accW = fmaf(bfh(xb), v.w, accW);
      }
#pragma unroll
      for (int m = 16; m >= 1; m >>= 1) {
        accG += __shfl_xor(accG, m, 64);
        accW += __shfl_xor(accW, m, 64);
      }
      if (chunk == 0) { corrLDS[row_local] = accG; wrLDS[row_local] = accW; }
      __syncthreads();

      // ---- z-update for this block's 8 rows ----
      if (tid < 8) {
        if (j == 0) {
          drive = wrLDS[tid] + cv;                          // Wr f(z_prev) + Win f(u)
          td[(size_t)(bid * 8 + tid) * SEQL + t] = f2bf(tanhf(drive));  // z_proj path
        }
        float corr = bv - corrLDS[tid];                     // Wout^T(x - Wout fz)
        float dz = (z - drive) - (1.f - fz * fz) * corr;
        z -= lr * dz;
        if (j == niters - 1) zs[(size_t)(bid * 8 + tid) * SEQL + t] = z;
        fz = tanhf(z);
        fzpack[tid] = f2bf(fz);
      }
      __syncthreads();

      // ---- publish own 8 fz values (16B) + flag ----
      if (tid == 0) {
        u64 lo = (u64)fzpack[0] | ((u64)fzpack[1] << 16) |
                 ((u64)fzpack[2] << 32) | ((u64)fzpack[3] << 48);
        u64 hi = (u64)fzpack[4] | ((u64)fzpack[5] << 16) |
                 ((u64)fzpack[6] << 32) | ((u64)fzpack[7] << 48);
        u64* dst = fzbuf + (size_t)(p & 1) * 512 + bid * 2;
        __hip_atomic_store(dst,     lo, __ATOMIC_RELAXED, __HIP_MEMORY_SCOPE_AGENT);
        __hip_atomic_store(dst + 1, hi, __ATOMIC_RELAXED, __HIP_MEMORY_SCOPE_AGENT);
        __hip_atomic_store(&flags[bid], p, __ATOMIC_RELEASE, __HIP_MEMORY_SCOPE_AGENT);
      }

      // ---- poll all 256 flags (one per thread), bounded to avoid hangs ----
      int guard = 0;
      while (__hip_atomic_load(&flags[tid], __ATOMIC_ACQUIRE, __HIP_MEMORY_SCOPE_AGENT) < p) {
        if (++guard > 4000000) { sAbort = 1; break; }
      }

      // ---- gather full fz (bf16 -> fp32 into LDS) ----
      const u64* src = fzbuf + (size_t)(p & 1) * 512;
      u64 g0 = __hip_atomic_load(src + tid * 2,     __ATOMIC_RELAXED, __HIP_MEMORY_SCOPE_AGENT);
      u64 g1 = __hip_atomic_load(src + tid * 2 + 1, __ATOMIC_RELAXED, __HIP_MEMORY_SCOPE_AGENT);
      float* o = fzLDS + tid * 8;
      o[0] = bf2f((u16)g0);         o[1] = bf2f((u16)(g0 >> 16));
      o[2] = bf2f((u16)(g0 >> 32)); o[3] = bf2f((u16)(g0 >> 48));
      o[4] = bf2f((u16)g1);         o[5] = bf2f((u16)(g1 >> 16));
      o[6] = bf2f((u16)(g1 >> 32)); o[7] = bf2f((u16)(g1 >> 48));
      __syncthreads();
      if (sAbort) return;
    }
  }
}

// ---------------- host ----------------
extern "C" void kernel_launch(void* const* d_in, const int* in_sizes, int n_in,
                              void* d_out, int out_size, void* d_ws, size_t ws_size,
                              hipStream_t stream)
{
  const float* inputs   = (const float*)d_in[0];   // (1024, 4096)
  const float* controls = (const float*)d_in[1];   // (512, 4096)
  const float* Wr       = (const float*)d_in[2];   // (2048, 2048)
  const float* Win      = (const float*)d_in[3];   // (2048, 512)
  const float* Wout     = (const float*)d_in[4];   // (1024, 2048)
  const int*   itp      = (const int*)d_in[5];     // 20
  const float* lrp      = (const float*)d_in[6];   // 0.05
  float* out = (float*)d_out;
  char* ws = (char*)d_ws;

  size_t off = 0;
  u16* WrB   = (u16*)(ws + off); off += (size_t)NLAT * NLAT * 2;  // 8 MB
  u16* WoutB = (u16*)(ws + off); off += (size_t)NOBS * NLAT * 2;  // 4 MB
  u16* WinB  = (u16*)(ws + off); off += (size_t)NLAT * NCTL * 2;  // 2 MB
  u16* XB    = (u16*)(ws + off); off += (size_t)NOBS * SEQL * 2;  // 8 MB
  u16* UB    = (u16*)(ws + off); off += (size_t)NCTL * SEQL * 2;  // 4 MB
  u16* WoutT = (u16*)(ws + off); off += (size_t)NLAT * NOBS * 2;  // 4 MB
  u16* Gm    = (u16*)(ws + off); off += (size_t)NLAT * NLAT * 2;  // 8 MB
  u16* CinB  = (u16*)(ws + off); off += (size_t)NLAT * SEQL * 2;  // 16 MB
  u16* TD    = (u16*)(ws + off); off += (size_t)NLAT * SEQL * 2;  // 16 MB
  u32* flags = (u32*)(ws + off); off += 1024;
  u64* fzbuf = (u64*)(ws + off); off += 2 * 512 * 8;
  // total ~73.4 MB of ws

  float* zs   = out;                        // (2048, 4096) f32
  float* pred = out + (size_t)NLAT * SEQL;  // (1024, 4096) f32
  u16* BmatB  = (u16*)pred;  // B = Wout^T @ inputs, bf16 2048x4096 = 16MB, overlays pred
                             // region; consumed by scan, then overwritten by final GEMM.

  // Stage 1: converts / transpose (all parallel, tiny)
  k_f2b   <<<(NLAT * NLAT + 255) / 256, 256, 0, stream>>>(Wr,    WrB,   NLAT * NLAT);
  k_f2b   <<<(NOBS * NLAT + 255) / 256, 256, 0, stream>>>(Wout,  WoutB, NOBS * NLAT);
  k_f2b   <<<(NLAT * NCTL + 255) / 256, 256, 0, stream>>>(Win,   WinB,  NLAT * NCTL);
  k_f2b   <<<(NOBS * SEQL + 255) / 256, 256, 0, stream>>>(inputs, XB,   NOBS * SEQL);
  k_tanh2b<<<(NCTL * SEQL + 255) / 256, 256, 0, stream>>>(controls, UB, NCTL * SEQL);
  k_tr2b  <<<(NOBS * NLAT + 255) / 256, 256, 0, stream>>>(Wout, WoutT, NOBS, NLAT);

  // Stage 2: precompute GEMMs
  gemm_bf16<<<dim3(NLAT / 64, NLAT / 64), 256, 0, stream>>>(WoutT, WoutB, nullptr, Gm,
                                                            NLAT, NLAT, NOBS);
  gemm_bf16<<<dim3(SEQL / 64, NLAT / 64), 256, 0, stream>>>(WoutT, XB, nullptr, BmatB,
                                                            NLAT, SEQL, NOBS);
  gemm_bf16<<<dim3(SEQL / 64, NLAT / 64), 256, 0, stream>>>(WinB, UB, nullptr, CinB,
                                                            NLAT, SEQL, NCTL);

  // Stage 3: sequential scan (cooperative so all 256 blocks are co-resident)
  hipMemsetAsync(flags, 0, 1024, stream);
  const u16* Gc = Gm; const u16* Wrc = WrB; const u16* Bc = BmatB; const u16* Cc = CinB;
  float* zsp = zs; u16* tdp = TD; u32* fp = flags; u64* fzp = fzbuf;
  const int* it = itp; const float* lr = lrp;
  void* args[10] = { &Gc, &Wrc, &Bc, &Cc, &zsp, &tdp, &fp, &fzp, &it, &lr };
  hipLaunchCooperativeKernel((void*)scan_kernel, dim3(NLAT / 8), dim3(256), args, 0, stream);

  // Stage 4: pred_xs = Wout @ tanh(z_projs)  (overwrites BmatB region with fp32 output)
  gemm_bf16<<<dim3(SEQL / 64, NOBS / 64), 256, 0, stream>>>(WoutB, TD, pred, nullptr,
                                                            NOBS, SEQL, NLAT);
}

// Round 2
// 282361.035 us; speedup vs baseline: 7.8705x; 7.8705x over previous
//
#include <hip/hip_runtime.h>
#include <hip/hip_bf16.h>

// NeuralKalmanFilter scan: 4096 steps x 20 inference iters = 81920 sequential phases.
// Per phase: one 2048x2048 matvec (G = Wout^T Wout, precomputed) + z update + all-to-all
// broadcast of the 2048-vector fz across 256 blocks (1/CU).
// R2: fence-free broadcast. Each published u64 = tag(16b) | 3 x bf16. Readers poll with
// RELAXED agent-scope loads (no acquire -> no buffer_inv per iteration, which was R1's
// 27us/phase). Double-buffered by phase parity. Weights live as fp32 in VGPRs.

#define SEQL 4096
#define NLAT 2048
#define NOBS 1024
#define NCTL 512

typedef unsigned short u16;
typedef unsigned int   u32;
typedef unsigned long long u64;

__device__ __forceinline__ float bfl(u32 u)  { return __uint_as_float(u << 16); }
__device__ __forceinline__ float bfh(u32 u)  { return __uint_as_float(u & 0xffff0000u); }
__device__ __forceinline__ float bf2f(u16 s) { return __uint_as_float(((u32)s) << 16); }
__device__ __forceinline__ u16 f2bf(float f) {            // round-to-nearest-even bf16
  u32 x = __float_as_uint(f);
  return (u16)((x + 0x7fffu + ((x >> 16) & 1u)) >> 16);
}

// ---------------- elementwise converts ----------------
__global__ void k_f2b(const float* __restrict__ in, u16* __restrict__ out, int n) {
  int i = blockIdx.x * 256 + threadIdx.x;
  if (i < n) out[i] = f2bf(in[i]);
}
__global__ void k_tanh2b(const float* __restrict__ in, u16* __restrict__ out, int n) {
  int i = blockIdx.x * 256 + threadIdx.x;
  if (i < n) out[i] = f2bf(tanhf(in[i]));
}
// out[c*R + r] = bf16(in[r*C + c])   (build Wout^T)
__global__ void k_tr2b(const float* __restrict__ in, u16* __restrict__ out, int R, int C) {
  int i = blockIdx.x * 256 + threadIdx.x;
  if (i < R * C) {
    int r = i / C, c = i % C;
    out[(size_t)c * R + r] = f2bf(in[i]);
  }
}

// ---------------- simple LDS-tiled bf16 GEMM (fp32 acc), 64x64 tile ----------------
// C = A(MxK) @ B(KxN), all row-major. Writes fp32 (Cf) or bf16 (Cb); pass the other null.
__global__ __launch_bounds__(256) void gemm_bf16(
    const u16* __restrict__ A, const u16* __restrict__ B,
    float* __restrict__ Cf, u16* __restrict__ Cb, int M, int N, int K)
{
  __shared__ float As[32][68];
  __shared__ float Bs[32][68];
  const int tid = threadIdx.x;
  const int colBase = blockIdx.x * 64, rowBase = blockIdx.y * 64;
  const int tx = tid & 15, ty = tid >> 4;
  const int ar = tid >> 2, ak = (tid & 3) * 8;
  const int bk = tid >> 3, bc = (tid & 7) * 8;
  const u16* Ap = A + (size_t)(rowBase + ar) * K + ak;
  const u16* Bp = B + (size_t)bk * N + colBase + bc;
  float acc[4][4] = {};

  for (int k0 = 0; k0 < K; k0 += 32) {
    uint4 a = *(const uint4*)(Ap + k0);
    uint4 b = *(const uint4*)(Bp + (size_t)k0 * N);
    As[ak + 0][ar] = bfl(a.x); As[ak + 1][ar] = bfh(a.x);
    As[ak + 2][ar] = bfl(a.y); As[ak + 3][ar] = bfh(a.y);
    As[ak + 4][ar] = bfl(a.z); As[ak + 5][ar] = bfh(a.z);
    As[ak + 6][ar] = bfl(a.w); As[ak + 7][ar] = bfh(a.w);
    Bs[bk][bc + 0] = bfl(b.x); Bs[bk][bc + 1] = bfh(b.x);
    Bs[bk][bc + 2] = bfl(b.y); Bs[bk][bc + 3] = bfh(b.y);
    Bs[bk][bc + 4] = bfl(b.z); Bs[bk][bc + 5] = bfh(b.z);
    Bs[bk][bc + 6] = bfl(b.w); Bs[bk][bc + 7] = bfh(b.w);
    __syncthreads();
#pragma unroll
    for (int kk = 0; kk < 32; kk++) {
      float4 av = *(const float4*)&As[kk][ty * 4];
      float4 bv = *(const float4*)&Bs[kk][tx * 4];
      float a4[4] = {av.x, av.y, av.z, av.w};
      float b4[4] = {bv.x, bv.y, bv.z, bv.w};
#pragma unroll
      for (int i = 0; i < 4; i++)
#pragma unroll
        for (int q = 0; q < 4; q++)
          acc[i][q] = fmaf(a4[i], b4[q], acc[i][q]);
    }
    __syncthreads();
  }

  if (Cf) {
#pragma unroll
    for (int i = 0; i < 4; i++) {
      float4 v = make_float4(acc[i][0], acc[i][1], acc[i][2], acc[i][3]);
      *(float4*)&Cf[(size_t)(rowBase + ty * 4 + i) * N + colBase + tx * 4] = v;
    }
  } else {
#pragma unroll
    for (int i = 0; i < 4; i++) {
      u64 pk = (u64)f2bf(acc[i][0]) | ((u64)f2bf(acc[i][1]) << 16) |
               ((u64)f2bf(acc[i][2]) << 32) | ((u64)f2bf(acc[i][3]) << 48);
      *(u64*)&Cb[(size_t)(rowBase + ty * 4 + i) * N + colBase + tx * 4] = pk;
    }
  }
}

// ---------------- the sequential scan (cooperative, 256 blocks x 256 threads) ----------
__global__ void __launch_bounds__(256, 1)
scan_kernel(const float* __restrict__ G,      // 2048x2048 f32  (Wout^T Wout)
            const float* __restrict__ Wr,     // 2048x2048 f32  (original input)
            const u16* __restrict__ Bmat,     // 2048x4096 bf16 (Wout^T @ inputs)
            const u16* __restrict__ Cin,      // 2048x4096 bf16 (Win @ tanh(controls))
            float* __restrict__ zs,           // 2048x4096 f32 out
            u16* __restrict__ td,             // 2048x4096 bf16 out: tanh(drive)
            u64* __restrict__ fzbuf,          // 2 parities x 256 blocks x 3 words
            const int* __restrict__ itp, const float* __restrict__ lrp)
{
  __shared__ __align__(16) float fzLDS[NLAT];   // current fz, fp32
  __shared__ float corrLDS[8], wrLDS[8];
  __shared__ int sAbort;

  const int tid = threadIdx.x, bid = blockIdx.x;
  const int lane = tid & 63, wave = tid >> 6;
  const int row_local = wave * 2 + (lane >> 5);    // 0..7
  const int chunk = lane & 31;                     // 0..31
  const int row = bid * 8 + row_local;
  const int row8 = bid * 8 + lane;                 // valid for lane < 8

  const int niters = *itp;       // 20
  const float lr = *lrp;         // 0.05

  // Per-thread fp32 weight slice in VGPRs: columns chunk*4 + 128*i + (0..3), i=0..15.
  // This column swizzle makes the LDS matvec reads bank-conflict-free (each 8-lane
  // group of a row spans all 32 banks).
  float4 wG4[16], wW4[16];
  {
    const float* gRow = G  + (size_t)row * NLAT + chunk * 4;
    const float* wRow = Wr + (size_t)row * NLAT + chunk * 4;
#pragma unroll
    for (int i = 0; i < 16; i++) {
      wG4[i] = *(const float4*)(gRow + 128 * i);
      wW4[i] = *(const float4*)(wRow + 128 * i);
    }
  }
  for (int i = tid; i < NLAT; i += 256) fzLDS[i] = 0.f;   // z0 = 0 -> fz = 0
  if (tid == 0) sAbort = 0;

  float z = 0.f, fz = 0.f, drive = 0.f, bv = 0.f;   // live in lanes<8 of wave 0
  float bvN = 0.f, cvN = 0.f;
  if (wave == 0 && lane < 8) {                      // prefetch step-0 columns
    bvN = bf2f(Bmat[(size_t)row8 * SEQL]);
    cvN = bf2f(Cin [(size_t)row8 * SEQL]);
  }
  __syncthreads();

  u32 p = 0;
  for (int t = 0; t < SEQL; t++) {
    for (int j = 0; j < niters; j++) {
      p++;
      // ---- matvec on fzLDS (holds fz after phase p-1) ----
      float accG = 0.f, accW = 0.f;
      const float4* f4 = (const float4*)(fzLDS + chunk * 4);
      if (j == 0) {
#pragma unroll
        for (int i = 0; i < 16; i++) {
          float4 v = f4[32 * i];
          float4 g = wG4[i], w = wW4[i];
          accG = fmaf(g.x, v.x, accG); accG = fmaf(g.y, v.y, accG);
          accG = fmaf(g.z, v.z, accG); accG = fmaf(g.w, v.w, accG);
          accW = fmaf(w.x, v.x, accW); accW = fmaf(w.y, v.y, accW);
          accW = fmaf(w.z, v.z, accW); accW = fmaf(w.w, v.w, accW);
        }
      } else {
#pragma unroll
        for (int i = 0; i < 16; i++) {
          float4 v = f4[32 * i];
          float4 g = wG4[i];
          accG = fmaf(g.x, v.x, accG); accG = fmaf(g.y, v.y, accG);
          accG = fmaf(g.z, v.z, accG); accG = fmaf(g.w, v.w, accG);
        }
      }
#pragma unroll
      for (int m = 16; m; m >>= 1) accG += __shfl_xor(accG, m, 64);
      if (j == 0) {
#pragma unroll
        for (int m = 16; m; m >>= 1) accW += __shfl_xor(accW, m, 64);
      }
      if (chunk == 0) {
        corrLDS[row_local] = accG;
        if (j == 0) wrLDS[row_local] = accW;
      }
      __syncthreads();   // corrLDS ready; also: all matvec reads of fzLDS are done

      // ---- wave 0: z-update + publish; waves 1-3 fall through to poll ----
      if (wave == 0) {
        u32 myfz = 0;
        if (lane < 8) {
          if (j == 0) { bv = bvN; drive = wrLDS[lane] + cvN; }
          float corr = bv - corrLDS[lane];              // (Wout^T(x - Wout fz))[row]
          float dz = (z - drive) - (1.f - fz * fz) * corr;
          z -= lr * dz;
          if (j == niters - 1) zs[(size_t)row8 * SEQL + t] = z;
          fz = tanhf(z);
          myfz = f2bf(fz);
        }
        // gather 3 values per word via in-wave shuffles, publish tag-in-data words
        int s0 = (3 * lane) & 63;
        u32 a = __shfl((int)myfz, s0, 64);
        u32 b = __shfl((int)myfz, (s0 + 1) & 63, 64);
        u32 c = __shfl((int)myfz, (s0 + 2) & 63, 64);
        if (lane < 3) {
          u64 word = (u64)(u16)p | ((u64)a << 16) | ((u64)b << 32) | ((u64)c << 48);
          __hip_atomic_store(&fzbuf[(((size_t)(p & 1) * 256 + bid) * 3) + lane], word,
                             __ATOMIC_RELAXED, __HIP_MEMORY_SCOPE_AGENT);
        }
        if (lane < 8 && j == 0) {       // off the publish critical path
          td[(size_t)row8 * SEQL + t] = f2bf(tanhf(drive));
          int tn = t + 1 < SEQL ? t + 1 : t;
          bvN = bf2f(Bmat[(size_t)row8 * SEQL + tn]);
          cvN = bf2f(Cin [(size_t)row8 * SEQL + tn]);
        }
      }

      // ---- poll: thread tid reads block tid's 3 words (relaxed, no fences) ----
      const u64* src = fzbuf + ((size_t)(p & 1) * 256 + tid) * 3;
      u16 want = (u16)p;
      u64 g0 = __hip_atomic_load(src + 0, __ATOMIC_RELAXED, __HIP_MEMORY_SCOPE_AGENT);
      u64 g1 = __hip_atomic_load(src + 1, __ATOMIC_RELAXED, __HIP_MEMORY_SCOPE_AGENT);
      u64 g2 = __hip_atomic_load(src + 2, __ATOMIC_RELAXED, __HIP_MEMORY_SCOPE_AGENT);
      int guard = 0;
      while ((u16)g0 != want || (u16)g1 != want || (u16)g2 != want) {
        if (++guard > 1000000) { sAbort = 1; break; }
        if ((u16)g0 != want)
          g0 = __hip_atomic_load(src + 0, __ATOMIC_RELAXED, __HIP_MEMORY_SCOPE_AGENT);
        if ((u16)g1 != want)
          g1 = __hip_atomic_load(src + 1, __ATOMIC_RELAXED, __HIP_MEMORY_SCOPE_AGENT);
        if ((u16)g2 != want)
          g2 = __hip_atomic_load(src + 2, __ATOMIC_RELAXED, __HIP_MEMORY_SCOPE_AGENT);
      }

      // ---- unpack straight into fzLDS (thread tid owns rows tid*8..tid*8+7) ----
      float* o = fzLDS + tid * 8;
      o[0] = bf2f((u16)(g0 >> 16)); o[1] = bf2f((u16)(g0 >> 32)); o[2] = bf2f((u16)(g0 >> 48));
      o[3] = bf2f((u16)(g1 >> 16)); o[4] = bf2f((u16)(g1 >> 32)); o[5] = bf2f((u16)(g1 >> 48));
      o[6] = bf2f((u16)(g2 >> 16)); o[7] = bf2f((u16)(g2 >> 32));
      __syncthreads();   // fzLDS ready for next phase
      if (sAbort) return;
    }
  }
}

// ---------------- host ----------------
extern "C" void kernel_launch(void* const* d_in, const int* in_sizes, int n_in,
                              void* d_out, int out_size, void* d_ws, size_t ws_size,
                              hipStream_t stream)
{
  const float* inputs   = (const float*)d_in[0];   // (1024, 4096)
  const float* controls = (const float*)d_in[1];   // (512, 4096)
  const float* Wr       = (const float*)d_in[2];   // (2048, 2048)
  const float* Win      = (const float*)d_in[3];   // (2048, 512)
  const float* Wout     = (const float*)d_in[4];   // (1024, 2048)
  const int*   itp      = (const int*)d_in[5];     // 20
  const float* lrp      = (const float*)d_in[6];   // 0.05
  float* out = (float*)d_out;
  char* ws = (char*)d_ws;

  size_t off = 0;
  u16*   WoutB = (u16*)(ws + off);   off += (size_t)NOBS * NLAT * 2;  // 4 MB
  u16*   WinB  = (u16*)(ws + off);   off += (size_t)NLAT * NCTL * 2;  // 2 MB
  u16*   XB    = (u16*)(ws + off);   off += (size_t)NOBS * SEQL * 2;  // 8 MB
  u16*   UB    = (u16*)(ws + off);   off += (size_t)NCTL * SEQL * 2;  // 4 MB
  u16*   WoutT = (u16*)(ws + off);   off += (size_t)NLAT * NOBS * 2;  // 4 MB
  float* Gf    = (float*)(ws + off); off += (size_t)NLAT * NLAT * 4;  // 16 MB
  u16*   CinB  = (u16*)(ws + off);   off += (size_t)NLAT * SEQL * 2;  // 16 MB
  u16*   TD    = (u16*)(ws + off);   off += (size_t)NLAT * SEQL * 2;  // 16 MB
  u64*   fzbuf = (u64*)(ws + off);   off += (size_t)2 * 256 * 3 * 8;  // 12 KB
  // total ~70 MB of ws

  float* zs   = out;                        // (2048, 4096) f32
  float* pred = out + (size_t)NLAT * SEQL;  // (1024, 4096) f32
  u16* BmatB  = (u16*)pred;  // B = Wout^T @ inputs (bf16, 16MB) overlays pred region;
                             // consumed by scan, then overwritten by the final GEMM.

  // Stage 1: converts / transpose
  k_f2b   <<<(NOBS * NLAT + 255) / 256, 256, 0, stream>>>(Wout,  WoutB, NOBS * NLAT);
  k_f2b   <<<(NLAT * NCTL + 255) / 256, 256, 0, stream>>>(Win,   WinB,  NLAT * NCTL);
  k_f2b   <<<(NOBS * SEQL + 255) / 256, 256, 0, stream>>>(inputs, XB,   NOBS * SEQL);
  k_tanh2b<<<(NCTL * SEQL + 255) / 256, 256, 0, stream>>>(controls, UB, NCTL * SEQL);
  k_tr2b  <<<(NOBS * NLAT + 255) / 256, 256, 0, stream>>>(Wout, WoutT, NOBS, NLAT);

  // Stage 2: precompute GEMMs (G in fp32)
  gemm_bf16<<<dim3(NLAT / 64, NLAT / 64), 256, 0, stream>>>(WoutT, WoutB, Gf, nullptr,
                                                            NLAT, NLAT, NOBS);
  gemm_bf16<<<dim3(SEQL / 64, NLAT / 64), 256, 0, stream>>>(WoutT, XB, nullptr, BmatB,
                                                            NLAT, SEQL, NOBS);
  gemm_bf16<<<dim3(SEQL / 64, NLAT / 64), 256, 0, stream>>>(WinB, UB, nullptr, CinB,
                                                            NLAT, SEQL, NCTL);

  // Stage 3: sequential scan (cooperative so all 256 blocks are co-resident)
  const float* Gc = Gf; const float* Wrc = Wr; const u16* Bc = BmatB; const u16* Cc = CinB;
  float* zsp = zs; u16* tdp = TD; u64* fzp = fzbuf;
  const int* it = itp; const float* lr = lrp;
  void* args[9] = { &Gc, &Wrc, &Bc, &Cc, &zsp, &tdp, &fzp, &it, &lr };
  hipLaunchCooperativeKernel((void*)scan_kernel, dim3(NLAT / 8), dim3(256), args, 0, stream);

  // Stage 4: pred_xs = Wout @ tanh(z_projs)
  gemm_bf16<<<dim3(SEQL / 64, NOBS / 64), 256, 0, stream>>>(WoutB, TD, pred, nullptr,
                                                            NOBS, SEQL, NLAT);
}

// Round 3
// 234931.299 us; speedup vs baseline: 9.4595x; 1.2019x over previous
//
#include <hip/hip_runtime.h>
#include <hip/hip_bf16.h>

// NeuralKalmanFilter scan: 4096 steps x 20 inference iters = 81920 sequential phases.
// Per phase: one 2048x2048 matvec (G = Wout^T Wout, precomputed) + z update + all-to-all
// broadcast of the 2048-vector fz across 256 blocks (1/CU).
// R3: lane-coalesced polling. fzbuf words (tag16 | 3 x bf16) unchanged, but reader thread
// tid polls words {tid, tid+256, tid+512} so each poll instruction is 64 contiguous lanes
// = 512B fully coalesced (R2's tid*3+k stride caused ~3x redundant LLC transactions on 48
// hot lines -> serialization at the coherence point). Packed fp32 FMA in the matvec.

#define SEQL 4096
#define NLAT 2048
#define NOBS 1024
#define NCTL 512

typedef unsigned short u16;
typedef unsigned int   u32;
typedef unsigned long long u64;
typedef float v2f __attribute__((ext_vector_type(2)));

__device__ __forceinline__ float bfl(u32 u)  { return __uint_as_float(u << 16); }
__device__ __forceinline__ float bfh(u32 u)  { return __uint_as_float(u & 0xffff0000u); }
__device__ __forceinline__ float bf2f(u16 s) { return __uint_as_float(((u32)s) << 16); }
__device__ __forceinline__ u16 f2bf(float f) {            // round-to-nearest-even bf16
  u32 x = __float_as_uint(f);
  return (u16)((x + 0x7fffu + ((x >> 16) & 1u)) >> 16);
}

#if __has_builtin(__builtin_elementwise_fma)
__device__ __forceinline__ v2f pkfma(v2f a, v2f b, v2f c) {
  return __builtin_elementwise_fma(a, b, c);
}
#else
__device__ __forceinline__ v2f pkfma(v2f a, v2f b, v2f c) {
  v2f r; r.x = fmaf(a.x, b.x, c.x); r.y = fmaf(a.y, b.y, c.y); return r;
}
#endif

// ---------------- elementwise converts ----------------
__global__ void k_f2b(const float* __restrict__ in, u16* __restrict__ out, int n) {
  int i = blockIdx.x * 256 + threadIdx.x;
  if (i < n) out[i] = f2bf(in[i]);
}
__global__ void k_tanh2b(const float* __restrict__ in, u16* __restrict__ out, int n) {
  int i = blockIdx.x * 256 + threadIdx.x;
  if (i < n) out[i] = f2bf(tanhf(in[i]));
}
// out[c*R + r] = bf16(in[r*C + c])   (build Wout^T)
__global__ void k_tr2b(const float* __restrict__ in, u16* __restrict__ out, int R, int C) {
  int i = blockIdx.x * 256 + threadIdx.x;
  if (i < R * C) {
    int r = i / C, c = i % C;
    out[(size_t)c * R + r] = f2bf(in[i]);
  }
}

// ---------------- simple LDS-tiled bf16 GEMM (fp32 acc), 64x64 tile ----------------
__global__ __launch_bounds__(256) void gemm_bf16(
    const u16* __restrict__ A, const u16* __restrict__ B,
    float* __restrict__ Cf, u16* __restrict__ Cb, int M, int N, int K)
{
  __shared__ float As[32][68];
  __shared__ float Bs[32][68];
  const int tid = threadIdx.x;
  const int colBase = blockIdx.x * 64, rowBase = blockIdx.y * 64;
  const int tx = tid & 15, ty = tid >> 4;
  const int ar = tid >> 2, ak = (tid & 3) * 8;
  const int bk = tid >> 3, bc = (tid & 7) * 8;
  const u16* Ap = A + (size_t)(rowBase + ar) * K + ak;
  const u16* Bp = B + (size_t)bk * N + colBase + bc;
  float acc[4][4] = {};

  for (int k0 = 0; k0 < K; k0 += 32) {
    uint4 a = *(const uint4*)(Ap + k0);
    uint4 b = *(const uint4*)(Bp + (size_t)k0 * N);
    As[ak + 0][ar] = bfl(a.x); As[ak + 1][ar] = bfh(a.x);
    As[ak + 2][ar] = bfl(a.y); As[ak + 3][ar] = bfh(a.y);
    As[ak + 4][ar] = bfl(a.z); As[ak + 5][ar] = bfh(a.z);
    As[ak + 6][ar] = bfl(a.w); As[ak + 7][ar] = bfh(a.w);
    Bs[bk][bc + 0] = bfl(b.x); Bs[bk][bc + 1] = bfh(b.x);
    Bs[bk][bc + 2] = bfl(b.y); Bs[bk][bc + 3] = bfh(b.y);
    Bs[bk][bc + 4] = bfl(b.z); Bs[bk][bc + 5] = bfh(b.z);
    Bs[bk][bc + 6] = bfl(b.w); Bs[bk][bc + 7] = bfh(b.w);
    __syncthreads();
#pragma unroll
    for (int kk = 0; kk < 32; kk++) {
      float4 av = *(const float4*)&As[kk][ty * 4];
      float4 bv = *(const float4*)&Bs[kk][tx * 4];
      float a4[4] = {av.x, av.y, av.z, av.w};
      float b4[4] = {bv.x, bv.y, bv.z, bv.w};
#pragma unroll
      for (int i = 0; i < 4; i++)
#pragma unroll
        for (int q = 0; q < 4; q++)
          acc[i][q] = fmaf(a4[i], b4[q], acc[i][q]);
    }
    __syncthreads();
  }

  if (Cf) {
#pragma unroll
    for (int i = 0; i < 4; i++) {
      float4 v = make_float4(acc[i][0], acc[i][1], acc[i][2], acc[i][3]);
      *(float4*)&Cf[(size_t)(rowBase + ty * 4 + i) * N + colBase + tx * 4] = v;
    }
  } else {
#pragma unroll
    for (int i = 0; i < 4; i++) {
      u64 pk = (u64)f2bf(acc[i][0]) | ((u64)f2bf(acc[i][1]) << 16) |
               ((u64)f2bf(acc[i][2]) << 32) | ((u64)f2bf(acc[i][3]) << 48);
      *(u64*)&Cb[(size_t)(rowBase + ty * 4 + i) * N + colBase + tx * 4] = pk;
    }
  }
}

// ---------------- the sequential scan (cooperative, 256 blocks x 256 threads) ----------
__global__ void __launch_bounds__(256, 1)
scan_kernel(const float* __restrict__ G,      // 2048x2048 f32  (Wout^T Wout)
            const float* __restrict__ Wr,     // 2048x2048 f32  (original input)
            const u16* __restrict__ Bmat,     // 2048x4096 bf16 (Wout^T @ inputs)
            const u16* __restrict__ Cin,      // 2048x4096 bf16 (Win @ tanh(controls))
            float* __restrict__ zs,           // 2048x4096 f32 out
            u16* __restrict__ td,             // 2048x4096 bf16 out: tanh(drive)
            u64* __restrict__ fzbuf,          // 2 parities x 768 words (tag|3xbf16)
            const int* __restrict__ itp, const float* __restrict__ lrp)
{
  __shared__ __align__(16) float fzLDS[NLAT];   // current fz, fp32
  __shared__ float corrLDS[8], wrLDS[8];
  __shared__ int sAbort;

  const int tid = threadIdx.x, bid = blockIdx.x;
  const int lane = tid & 63, wave = tid >> 6;
  const int row_local = wave * 2 + (lane >> 5);    // 0..7
  const int chunk = lane & 31;                     // 0..31
  const int row = bid * 8 + row_local;
  const int row8 = bid * 8 + lane;                 // valid for lane < 8

  const int niters = *itp;       // 20
  const float lr = *lrp;         // 0.05

  // Per-thread fp32 weight slice in VGPRs: columns chunk*4 + 128*i + (0..3).
  float4 wG4[16], wW4[16];
  {
    const float* gRow = G  + (size_t)row * NLAT + chunk * 4;
    const float* wRow = Wr + (size_t)row * NLAT + chunk * 4;
#pragma unroll
    for (int i = 0; i < 16; i++) {
      wG4[i] = *(const float4*)(gRow + 128 * i);
      wW4[i] = *(const float4*)(wRow + 128 * i);
    }
  }
  for (int i = tid; i < NLAT; i += 256) fzLDS[i] = 0.f;   // z0 = 0 -> fz = 0
  if (tid == 0) sAbort = 0;

  // Hoisted unpack mapping for the 3 words this thread polls: w = tid, tid+256, tid+512.
  // Word w covers rows (w/3)*8 + (w%3)*3 .. +2 (slot 2 holds only 2 valid values).
  const int w0 = tid, w1 = tid + 256, w2 = tid + 512;
  float* o0; float* o1; float* o2; int s0_, s1_, s2_;
  {
    int b0 = w0 / 3; s0_ = w0 - b0 * 3; o0 = fzLDS + b0 * 8 + s0_ * 3;
    int b1 = w1 / 3; s1_ = w1 - b1 * 3; o1 = fzLDS + b1 * 8 + s1_ * 3;
    int b2 = w2 / 3; s2_ = w2 - b2 * 3; o2 = fzLDS + b2 * 8 + s2_ * 3;
  }

  float z = 0.f, fz = 0.f, drive = 0.f, bv = 0.f;   // live in lanes<8 of wave 0
  float bvN = 0.f, cvN = 0.f;
  if (wave == 0 && lane < 8) {                      // prefetch step-0 columns
    bvN = bf2f(Bmat[(size_t)row8 * SEQL]);
    cvN = bf2f(Cin [(size_t)row8 * SEQL]);
  }
  __syncthreads();

  u32 p = 0;
  for (int t = 0; t < SEQL; t++) {
    for (int j = 0; j < niters; j++) {
      p++;
      // ---- matvec on fzLDS (fz after phase p-1), packed fp32 FMA ----
      v2f aG = {0.f, 0.f}, aW = {0.f, 0.f};
      const float4* f4 = (const float4*)(fzLDS + chunk * 4);
      if (j == 0) {
#pragma unroll
        for (int i = 0; i < 16; i++) {
          float4 v = f4[32 * i];
          float4 g = wG4[i], w = wW4[i];
          v2f vlo = {v.x, v.y}, vhi = {v.z, v.w};
          aG = pkfma((v2f){g.x, g.y}, vlo, aG);
          aG = pkfma((v2f){g.z, g.w}, vhi, aG);
          aW = pkfma((v2f){w.x, w.y}, vlo, aW);
          aW = pkfma((v2f){w.z, w.w}, vhi, aW);
        }
      } else {
#pragma unroll
        for (int i = 0; i < 16; i++) {
          float4 v = f4[32 * i];
          float4 g = wG4[i];
          aG = pkfma((v2f){g.x, g.y}, (v2f){v.x, v.y}, aG);
          aG = pkfma((v2f){g.z, g.w}, (v2f){v.z, v.w}, aG);
        }
      }
      float accG = aG.x + aG.y, accW = aW.x + aW.y;
#pragma unroll
      for (int m = 16; m; m >>= 1) accG += __shfl_xor(accG, m, 64);
      if (j == 0) {
#pragma unroll
        for (int m = 16; m; m >>= 1) accW += __shfl_xor(accW, m, 64);
      }
      if (chunk == 0) {
        corrLDS[row_local] = accG;
        if (j == 0) wrLDS[row_local] = accW;
      }
      __syncthreads();   // corrLDS ready; all matvec reads of fzLDS done

      // ---- wave 0: z-update + publish; waves 1-3 fall through to poll ----
      if (wave == 0) {
        u32 myfz = 0;
        if (lane < 8) {
          if (j == 0) { bv = bvN; drive = wrLDS[lane] + cvN; }
          float corr = bv - corrLDS[lane];              // (Wout^T(x - Wout fz))[row]
          float dz = (z - drive) - (1.f - fz * fz) * corr;
          z -= lr * dz;
          fz = tanhf(z);
          myfz = f2bf(fz);
        }
        // pack 3 values per word via shuffles, publish tag-in-data words
        int sh = (3 * lane) & 63;
        u32 a = __shfl((int)myfz, sh, 64);
        u32 b = __shfl((int)myfz, (sh + 1) & 63, 64);
        u32 c = __shfl((int)myfz, (sh + 2) & 63, 64);
        if (lane < 3) {
          u64 word = (u64)(u16)p | ((u64)a << 16) | ((u64)b << 32) | ((u64)c << 48);
          __hip_atomic_store(&fzbuf[(size_t)(p & 1) * 768 + bid * 3 + lane], word,
                             __ATOMIC_RELAXED, __HIP_MEMORY_SCOPE_AGENT);
        }
        if (lane < 8) {                 // off the publish critical path
          if (j == 0) {
            td[(size_t)row8 * SEQL + t] = f2bf(tanhf(drive));
            int tn = t + 1 < SEQL ? t + 1 : t;
            bvN = bf2f(Bmat[(size_t)row8 * SEQL + tn]);
            cvN = bf2f(Cin [(size_t)row8 * SEQL + tn]);
          }
          if (j == niters - 1) zs[(size_t)row8 * SEQL + t] = z;
        }
      }

      // ---- poll: coalesced — thread tid reads words tid, tid+256, tid+512 ----
      const u64* base = fzbuf + (size_t)(p & 1) * 768;
      u16 want = (u16)p;
      u64 g0 = __hip_atomic_load(base + w0, __ATOMIC_RELAXED, __HIP_MEMORY_SCOPE_AGENT);
      u64 g1 = __hip_atomic_load(base + w1, __ATOMIC_RELAXED, __HIP_MEMORY_SCOPE_AGENT);
      u64 g2 = __hip_atomic_load(base + w2, __ATOMIC_RELAXED, __HIP_MEMORY_SCOPE_AGENT);
      int guard = 0;
      while ((u16)g0 != want || (u16)g1 != want || (u16)g2 != want) {
        if (++guard > 2000000) { sAbort = 1; break; }
        if ((u16)g0 != want)
          g0 = __hip_atomic_load(base + w0, __ATOMIC_RELAXED, __HIP_MEMORY_SCOPE_AGENT);
        if ((u16)g1 != want)
          g1 = __hip_atomic_load(base + w1, __ATOMIC_RELAXED, __HIP_MEMORY_SCOPE_AGENT);
        if ((u16)g2 != want)
          g2 = __hip_atomic_load(base + w2, __ATOMIC_RELAXED, __HIP_MEMORY_SCOPE_AGENT);
      }

      // ---- unpack straight into fzLDS (slot-2 words carry only 2 valid values) ----
      o0[0] = bf2f((u16)(g0 >> 16)); o0[1] = bf2f((u16)(g0 >> 32));
      if (s0_ != 2) o0[2] = bf2f((u16)(g0 >> 48));
      o1[0] = bf2f((u16)(g1 >> 16)); o1[1] = bf2f((u16)(g1 >> 32));
      if (s1_ != 2) o1[2] = bf2f((u16)(g1 >> 48));
      o2[0] = bf2f((u16)(g2 >> 16)); o2[1] = bf2f((u16)(g2 >> 32));
      if (s2_ != 2) o2[2] = bf2f((u16)(g2 >> 48));
      __syncthreads();   // fzLDS ready for next phase
      if (sAbort) return;
    }
  }
}

// ---------------- host ----------------
extern "C" void kernel_launch(void* const* d_in, const int* in_sizes, int n_in,
                              void* d_out, int out_size, void* d_ws, size_t ws_size,
                              hipStream_t stream)
{
  const float* inputs   = (const float*)d_in[0];   // (1024, 4096)
  const float* controls = (const float*)d_in[1];   // (512, 4096)
  const float* Wr       = (const float*)d_in[2];   // (2048, 2048)
  const float* Win      = (const float*)d_in[3];   // (2048, 512)
  const float* Wout     = (const float*)d_in[4];   // (1024, 2048)
  const int*   itp      = (const int*)d_in[5];     // 20
  const float* lrp      = (const float*)d_in[6];   // 0.05
  float* out = (float*)d_out;
  char* ws = (char*)d_ws;

  size_t off = 0;
  u16*   WoutB = (u16*)(ws + off);   off += (size_t)NOBS * NLAT * 2;  // 4 MB
  u16*   WinB  = (u16*)(ws + off);   off += (size_t)NLAT * NCTL * 2;  // 2 MB
  u16*   XB    = (u16*)(ws + off);   off += (size_t)NOBS * SEQL * 2;  // 8 MB
  u16*   UB    = (u16*)(ws + off);   off += (size_t)NCTL * SEQL * 2;  // 4 MB
  u16*   WoutT = (u16*)(ws + off);   off += (size_t)NLAT * NOBS * 2;  // 4 MB
  float* Gf    = (float*)(ws + off); off += (size_t)NLAT * NLAT * 4;  // 16 MB
  u16*   CinB  = (u16*)(ws + off);   off += (size_t)NLAT * SEQL * 2;  // 16 MB
  u16*   TD    = (u16*)(ws + off);   off += (size_t)NLAT * SEQL * 2;  // 16 MB
  u64*   fzbuf = (u64*)(ws + off);   off += (size_t)2 * 768 * 8;      // 12 KB

  float* zs   = out;                        // (2048, 4096) f32
  float* pred = out + (size_t)NLAT * SEQL;  // (1024, 4096) f32
  u16* BmatB  = (u16*)pred;  // B = Wout^T @ inputs (bf16, 16MB) overlays pred region;
                             // consumed by scan, then overwritten by the final GEMM.

  // Stage 1: converts / transpose
  k_f2b   <<<(NOBS * NLAT + 255) / 256, 256, 0, stream>>>(Wout,  WoutB, NOBS * NLAT);
  k_f2b   <<<(NLAT * NCTL + 255) / 256, 256, 0, stream>>>(Win,   WinB,  NLAT * NCTL);
  k_f2b   <<<(NOBS * SEQL + 255) / 256, 256, 0, stream>>>(inputs, XB,   NOBS * SEQL);
  k_tanh2b<<<(NCTL * SEQL + 255) / 256, 256, 0, stream>>>(controls, UB, NCTL * SEQL);
  k_tr2b  <<<(NOBS * NLAT + 255) / 256, 256, 0, stream>>>(Wout, WoutT, NOBS, NLAT);

  // Stage 2: precompute GEMMs (G in fp32)
  gemm_bf16<<<dim3(NLAT / 64, NLAT / 64), 256, 0, stream>>>(WoutT, WoutB, Gf, nullptr,
                                                            NLAT, NLAT, NOBS);
  gemm_bf16<<<dim3(SEQL / 64, NLAT / 64), 256, 0, stream>>>(WoutT, XB, nullptr, BmatB,
                                                            NLAT, SEQL, NOBS);
  gemm_bf16<<<dim3(SEQL / 64, NLAT / 64), 256, 0, stream>>>(WinB, UB, nullptr, CinB,
                                                            NLAT, SEQL, NCTL);

  // Stage 3: sequential scan (cooperative so all 256 blocks are co-resident)
  const float* Gc = Gf; const float* Wrc = Wr; const u16* Bc = BmatB; const u16* Cc = CinB;
  float* zsp = zs; u16* tdp = TD; u64* fzp = fzbuf;
  const int* it = itp; const float* lr = lrp;
  void* args[9] = { &Gc, &Wrc, &Bc, &Cc, &zsp, &tdp, &fzp, &it, &lr };
  hipLaunchCooperativeKernel((void*)scan_kernel, dim3(NLAT / 8), dim3(256), args, 0, stream);

  // Stage 4: pred_xs = Wout @ tanh(z_projs)
  gemm_bf16<<<dim3(SEQL / 64, NOBS / 64), 256, 0, stream>>>(WoutB, TD, pred, nullptr,
                                                            NOBS, SEQL, NLAT);
}

// Round 4
// 206323.438 us; speedup vs baseline: 10.7711x; 1.1387x over previous
//
#include <hip/hip_runtime.h>
#include <hip/hip_bf16.h>

// NeuralKalmanFilter scan: 4096 steps x 20 inference iters = 81920 sequential phases.
// Per phase: one 2048x2048 matvec (G = Wout^T Wout, precomputed) + z update + all-to-all
// broadcast of the 2048-vector fz across 256 blocks (1/CU).
// R4: 8x-replicated fzbuf. R3 showed poll coalescing only bought 17% -> the contended
// resource is readers-per-MALL-line (256 blocks hammering the same 96 lines serialize at
// the slice and delay the publisher's write). Publisher writes 8 replicas in one 24-lane
// store; block bid polls replica bid&7 -> 32 readers/line. Plus branch-free tanh
// (v_exp+v_rcp) on the z-update critical path, s_setprio on the publisher wave, s_sleep
// backoff in the retry loop.

#define SEQL 4096
#define NLAT 2048
#define NOBS 1024
#define NCTL 512

typedef unsigned short u16;
typedef unsigned int   u32;
typedef unsigned long long u64;
typedef float v2f __attribute__((ext_vector_type(2)));

__device__ __forceinline__ float bfl(u32 u)  { return __uint_as_float(u << 16); }
__device__ __forceinline__ float bfh(u32 u)  { return __uint_as_float(u & 0xffff0000u); }
__device__ __forceinline__ float bf2f(u16 s) { return __uint_as_float(((u32)s) << 16); }
__device__ __forceinline__ u16 f2bf(float f) {            // round-to-nearest-even bf16
  u32 x = __float_as_uint(f);
  return (u16)((x + 0x7fffu + ((x >> 16) & 1u)) >> 16);
}

#if __has_builtin(__builtin_elementwise_fma)
__device__ __forceinline__ v2f pkfma(v2f a, v2f b, v2f c) {
  return __builtin_elementwise_fma(a, b, c);
}
#else
__device__ __forceinline__ v2f pkfma(v2f a, v2f b, v2f c) {
  v2f r; r.x = fmaf(a.x, b.x, c.x); r.y = fmaf(a.y, b.y, c.y); return r;
}
#endif

// Branch-free tanh: tanh(x) = 1 - 2/(exp2(2*log2e*x)+1). Saturates naturally at +-1
// (exp2 -> 0 or inf). ~1e-6 abs err, far below the bf16 broadcast quantization.
__device__ __forceinline__ float fast_tanh(float x) {
#if __has_builtin(__builtin_amdgcn_exp2f) && __has_builtin(__builtin_amdgcn_rcpf)
  float e = __builtin_amdgcn_exp2f(x * 2.8853900817779268f);
  return 1.f - 2.f * __builtin_amdgcn_rcpf(e + 1.f);
#else
  return tanhf(x);
#endif
}

// ---------------- elementwise converts ----------------
__global__ void k_f2b(const float* __restrict__ in, u16* __restrict__ out, int n) {
  int i = blockIdx.x * 256 + threadIdx.x;
  if (i < n) out[i] = f2bf(in[i]);
}
__global__ void k_tanh2b(const float* __restrict__ in, u16* __restrict__ out, int n) {
  int i = blockIdx.x * 256 + threadIdx.x;
  if (i < n) out[i] = f2bf(tanhf(in[i]));
}
// out[c*R + r] = bf16(in[r*C + c])   (build Wout^T)
__global__ void k_tr2b(const float* __restrict__ in, u16* __restrict__ out, int R, int C) {
  int i = blockIdx.x * 256 + threadIdx.x;
  if (i < R * C) {
    int r = i / C, c = i % C;
    out[(size_t)c * R + r] = f2bf(in[i]);
  }
}

// ---------------- simple LDS-tiled bf16 GEMM (fp32 acc), 64x64 tile ----------------
__global__ __launch_bounds__(256) void gemm_bf16(
    const u16* __restrict__ A, const u16* __restrict__ B,
    float* __restrict__ Cf, u16* __restrict__ Cb, int M, int N, int K)
{
  __shared__ float As[32][68];
  __shared__ float Bs[32][68];
  const int tid = threadIdx.x;
  const int colBase = blockIdx.x * 64, rowBase = blockIdx.y * 64;
  const int tx = tid & 15, ty = tid >> 4;
  const int ar = tid >> 2, ak = (tid & 3) * 8;
  const int bk = tid >> 3, bc = (tid & 7) * 8;
  const u16* Ap = A + (size_t)(rowBase + ar) * K + ak;
  const u16* Bp = B + (size_t)bk * N + colBase + bc;
  float acc[4][4] = {};

  for (int k0 = 0; k0 < K; k0 += 32) {
    uint4 a = *(const uint4*)(Ap + k0);
    uint4 b = *(const uint4*)(Bp + (size_t)k0 * N);
    As[ak + 0][ar] = bfl(a.x); As[ak + 1][ar] = bfh(a.x);
    As[ak + 2][ar] = bfl(a.y); As[ak + 3][ar] = bfh(a.y);
    As[ak + 4][ar] = bfl(a.z); As[ak + 5][ar] = bfh(a.z);
    As[ak + 6][ar] = bfl(a.w); As[ak + 7][ar] = bfh(a.w);
    Bs[bk][bc + 0] = bfl(b.x); Bs[bk][bc + 1] = bfh(b.x);
    Bs[bk][bc + 2] = bfl(b.y); Bs[bk][bc + 3] = bfh(b.y);
    Bs[bk][bc + 4] = bfl(b.z); Bs[bk][bc + 5] = bfh(b.z);
    Bs[bk][bc + 6] = bfl(b.w); Bs[bk][bc + 7] = bfh(b.w);
    __syncthreads();
#pragma unroll
    for (int kk = 0; kk < 32; kk++) {
      float4 av = *(const float4*)&As[kk][ty * 4];
      float4 bv = *(const float4*)&Bs[kk][tx * 4];
      float a4[4] = {av.x, av.y, av.z, av.w};
      float b4[4] = {bv.x, bv.y, bv.z, bv.w};
#pragma unroll
      for (int i = 0; i < 4; i++)
#pragma unroll
        for (int q = 0; q < 4; q++)
          acc[i][q] = fmaf(a4[i], b4[q], acc[i][q]);
    }
    __syncthreads();
  }

  if (Cf) {
#pragma unroll
    for (int i = 0; i < 4; i++) {
      float4 v = make_float4(acc[i][0], acc[i][1], acc[i][2], acc[i][3]);
      *(float4*)&Cf[(size_t)(rowBase + ty * 4 + i) * N + colBase + tx * 4] = v;
    }
  } else {
#pragma unroll
    for (int i = 0; i < 4; i++) {
      u64 pk = (u64)f2bf(acc[i][0]) | ((u64)f2bf(acc[i][1]) << 16) |
               ((u64)f2bf(acc[i][2]) << 32) | ((u64)f2bf(acc[i][3]) << 48);
      *(u64*)&Cb[(size_t)(rowBase + ty * 4 + i) * N + colBase + tx * 4] = pk;
    }
  }
}

// ---------------- the sequential scan (cooperative, 256 blocks x 256 threads) ----------
__global__ void __launch_bounds__(256, 1)
scan_kernel(const float* __restrict__ G,      // 2048x2048 f32  (Wout^T Wout)
            const float* __restrict__ Wr,     // 2048x2048 f32  (original input)
            const u16* __restrict__ Bmat,     // 2048x4096 bf16 (Wout^T @ inputs)
            const u16* __restrict__ Cin,      // 2048x4096 bf16 (Win @ tanh(controls))
            float* __restrict__ zs,           // 2048x4096 f32 out
            u16* __restrict__ td,             // 2048x4096 bf16 out: tanh(drive)
            u64* __restrict__ fzbuf,          // 2 parities x 8 replicas x 768 words
            const int* __restrict__ itp, const float* __restrict__ lrp)
{
  __shared__ __align__(16) float fzLDS[NLAT];   // current fz, fp32
  __shared__ float corrLDS[8], wrLDS[8];
  __shared__ int sAbort;

  const int tid = threadIdx.x, bid = blockIdx.x;
  const int lane = tid & 63, wave = tid >> 6;
  const int row_local = wave * 2 + (lane >> 5);    // 0..7
  const int chunk = lane & 31;                     // 0..31
  const int row = bid * 8 + row_local;
  const int row8 = bid * 8 + lane;                 // valid for lane < 8

  const int niters = *itp;       // 20
  const float lr = *lrp;         // 0.05

#if __has_builtin(__builtin_amdgcn_s_setprio)
  if (wave == 0) __builtin_amdgcn_s_setprio(1);    // publisher wave wins issue arbitration
#endif

  // Per-thread fp32 weight slice in VGPRs: columns chunk*4 + 128*i + (0..3).
  float4 wG4[16], wW4[16];
  {
    const float* gRow = G  + (size_t)row * NLAT + chunk * 4;
    const float* wRow = Wr + (size_t)row * NLAT + chunk * 4;
#pragma unroll
    for (int i = 0; i < 16; i++) {
      wG4[i] = *(const float4*)(gRow + 128 * i);
      wW4[i] = *(const float4*)(wRow + 128 * i);
    }
  }
  for (int i = tid; i < NLAT; i += 256) fzLDS[i] = 0.f;   // z0 = 0 -> fz = 0
  if (tid == 0) sAbort = 0;

  // Hoisted unpack mapping for the 3 words this thread polls: w = tid, tid+256, tid+512.
  // Word w covers rows (w/3)*8 + (w%3)*3 .. +2 (slot 2 holds only 2 valid values).
  const int w0 = tid, w1 = tid + 256, w2 = tid + 512;
  float* o0; float* o1; float* o2; int s0_, s1_, s2_;
  {
    int b0 = w0 / 3; s0_ = w0 - b0 * 3; o0 = fzLDS + b0 * 8 + s0_ * 3;
    int b1 = w1 / 3; s1_ = w1 - b1 * 3; o1 = fzLDS + b1 * 8 + s1_ * 3;
    int b2 = w2 / 3; s2_ = w2 - b2 * 3; o2 = fzLDS + b2 * 8 + s2_ * 3;
  }

  float z = 0.f, fz = 0.f, drive = 0.f, bv = 0.f;   // live in lanes<8 of wave 0
  float bvN = 0.f, cvN = 0.f;
  if (wave == 0 && lane < 8) {                      // prefetch step-0 columns
    bvN = bf2f(Bmat[(size_t)row8 * SEQL]);
    cvN = bf2f(Cin [(size_t)row8 * SEQL]);
  }
  __syncthreads();

  u32 p = 0;
  for (int t = 0; t < SEQL; t++) {
    for (int j = 0; j < niters; j++) {
      p++;
      // ---- matvec on fzLDS (fz after phase p-1), packed fp32 FMA ----
      v2f aG = {0.f, 0.f}, aW = {0.f, 0.f};
      const float4* f4 = (const float4*)(fzLDS + chunk * 4);
      if (j == 0) {
#pragma unroll
        for (int i = 0; i < 16; i++) {
          float4 v = f4[32 * i];
          float4 g = wG4[i], w = wW4[i];
          v2f vlo = {v.x, v.y}, vhi = {v.z, v.w};
          aG = pkfma((v2f){g.x, g.y}, vlo, aG);
          aG = pkfma((v2f){g.z, g.w}, vhi, aG);
          aW = pkfma((v2f){w.x, w.y}, vlo, aW);
          aW = pkfma((v2f){w.z, w.w}, vhi, aW);
        }
      } else {
#pragma unroll
        for (int i = 0; i < 16; i++) {
          float4 v = f4[32 * i];
          float4 g = wG4[i];
          aG = pkfma((v2f){g.x, g.y}, (v2f){v.x, v.y}, aG);
          aG = pkfma((v2f){g.z, g.w}, (v2f){v.z, v.w}, aG);
        }
      }
      float accG = aG.x + aG.y, accW = aW.x + aW.y;
#pragma unroll
      for (int m = 16; m; m >>= 1) accG += __shfl_xor(accG, m, 64);
      if (j == 0) {
#pragma unroll
        for (int m = 16; m; m >>= 1) accW += __shfl_xor(accW, m, 64);
      }
      if (chunk == 0) {
        corrLDS[row_local] = accG;
        if (j == 0) wrLDS[row_local] = accW;
      }
      __syncthreads();   // corrLDS ready; all matvec reads of fzLDS done

      // ---- wave 0: z-update + publish to 8 replicas; waves 1-3 fall through to poll ----
      if (wave == 0) {
        u32 myfz = 0;
        if (lane < 8) {
          if (j == 0) { bv = bvN; drive = wrLDS[lane] + cvN; }
          float corr = bv - corrLDS[lane];              // (Wout^T(x - Wout fz))[row]
          float dz = (z - drive) - (1.f - fz * fz) * corr;
          z -= lr * dz;
          fz = fast_tanh(z);
          myfz = f2bf(fz);
        }
        // pack 3 values per word via shuffles; lanes<24 write replica lane/3, slot lane%3
        int slot = lane % 3;
        u32 a = __shfl((int)myfz, 3 * slot, 64);
        u32 b = __shfl((int)myfz, 3 * slot + 1, 64);
        u32 c = __shfl((int)myfz, 3 * slot + 2, 64);
        if (lane < 24) {
          int rep = lane / 3;
          u64 word = (u64)(u16)p | ((u64)a << 16) | ((u64)b << 32) | ((u64)c << 48);
          __hip_atomic_store(
              &fzbuf[((size_t)(p & 1) * 8 + rep) * 768 + bid * 3 + slot], word,
              __ATOMIC_RELAXED, __HIP_MEMORY_SCOPE_AGENT);
        }
        if (lane < 8) {                 // off the publish critical path
          if (j == 0) {
            td[(size_t)row8 * SEQL + t] = f2bf(fast_tanh(drive));
            int tn = t + 1 < SEQL ? t + 1 : t;
            bvN = bf2f(Bmat[(size_t)row8 * SEQL + tn]);
            cvN = bf2f(Cin [(size_t)row8 * SEQL + tn]);
          }
          if (j == niters - 1) zs[(size_t)row8 * SEQL + t] = z;
        }
      }

      // ---- poll own replica (bid&7): thread tid reads words tid, tid+256, tid+512 ----
      const u64* base = fzbuf + ((size_t)(p & 1) * 8 + (bid & 7)) * 768;
      u16 want = (u16)p;
      u64 g0 = __hip_atomic_load(base + w0, __ATOMIC_RELAXED, __HIP_MEMORY_SCOPE_AGENT);
      u64 g1 = __hip_atomic_load(base + w1, __ATOMIC_RELAXED, __HIP_MEMORY_SCOPE_AGENT);
      u64 g2 = __hip_atomic_load(base + w2, __ATOMIC_RELAXED, __HIP_MEMORY_SCOPE_AGENT);
      int guard = 0;
      while ((u16)g0 != want || (u16)g1 != want || (u16)g2 != want) {
        if (++guard > 2000000) { sAbort = 1; break; }
#if __has_builtin(__builtin_amdgcn_s_sleep)
        __builtin_amdgcn_s_sleep(1);    // ~64cy backoff: fewer redundant in-flight reads
#endif
        if ((u16)g0 != want)
          g0 = __hip_atomic_load(base + w0, __ATOMIC_RELAXED, __HIP_MEMORY_SCOPE_AGENT);
        if ((u16)g1 != want)
          g1 = __hip_atomic_load(base + w1, __ATOMIC_RELAXED, __HIP_MEMORY_SCOPE_AGENT);
        if ((u16)g2 != want)
          g2 = __hip_atomic_load(base + w2, __ATOMIC_RELAXED, __HIP_MEMORY_SCOPE_AGENT);
      }

      // ---- unpack straight into fzLDS (slot-2 words carry only 2 valid values) ----
      o0[0] = bf2f((u16)(g0 >> 16)); o0[1] = bf2f((u16)(g0 >> 32));
      if (s0_ != 2) o0[2] = bf2f((u16)(g0 >> 48));
      o1[0] = bf2f((u16)(g1 >> 16)); o1[1] = bf2f((u16)(g1 >> 32));
      if (s1_ != 2) o1[2] = bf2f((u16)(g1 >> 48));
      o2[0] = bf2f((u16)(g2 >> 16)); o2[1] = bf2f((u16)(g2 >> 32));
      if (s2_ != 2) o2[2] = bf2f((u16)(g2 >> 48));
      __syncthreads();   // fzLDS ready for next phase
      if (sAbort) return;
    }
  }
}

// ---------------- host ----------------
extern "C" void kernel_launch(void* const* d_in, const int* in_sizes, int n_in,
                              void* d_out, int out_size, void* d_ws, size_t ws_size,
                              hipStream_t stream)
{
  const float* inputs   = (const float*)d_in[0];   // (1024, 4096)
  const float* controls = (const float*)d_in[1];   // (512, 4096)
  const float* Wr       = (const float*)d_in[2];   // (2048, 2048)
  const float* Win      = (const float*)d_in[3];   // (2048, 512)
  const float* Wout     = (const float*)d_in[4];   // (1024, 2048)
  const int*   itp      = (const int*)d_in[5];     // 20
  const float* lrp      = (const float*)d_in[6];   // 0.05
  float* out = (float*)d_out;
  char* ws = (char*)d_ws;

  size_t off = 0;
  u16*   WoutB = (u16*)(ws + off);   off += (size_t)NOBS * NLAT * 2;  // 4 MB
  u16*   WinB  = (u16*)(ws + off);   off += (size_t)NLAT * NCTL * 2;  // 2 MB
  u16*   XB    = (u16*)(ws + off);   off += (size_t)NOBS * SEQL * 2;  // 8 MB
  u16*   UB    = (u16*)(ws + off);   off += (size_t)NCTL * SEQL * 2;  // 4 MB
  u16*   WoutT = (u16*)(ws + off);   off += (size_t)NLAT * NOBS * 2;  // 4 MB
  float* Gf    = (float*)(ws + off); off += (size_t)NLAT * NLAT * 4;  // 16 MB
  u16*   CinB  = (u16*)(ws + off);   off += (size_t)NLAT * SEQL * 2;  // 16 MB
  u16*   TD    = (u16*)(ws + off);   off += (size_t)NLAT * SEQL * 2;  // 16 MB
  u64*   fzbuf = (u64*)(ws + off);   off += (size_t)2 * 8 * 768 * 8;  // 96 KB

  float* zs   = out;                        // (2048, 4096) f32
  float* pred = out + (size_t)NLAT * SEQL;  // (1024, 4096) f32
  u16* BmatB  = (u16*)pred;  // B = Wout^T @ inputs (bf16, 16MB) overlays pred region;
                             // consumed by scan, then overwritten by the final GEMM.

  // Stage 1: converts / transpose
  k_f2b   <<<(NOBS * NLAT + 255) / 256, 256, 0, stream>>>(Wout,  WoutB, NOBS * NLAT);
  k_f2b   <<<(NLAT * NCTL + 255) / 256, 256, 0, stream>>>(Win,   WinB,  NLAT * NCTL);
  k_f2b   <<<(NOBS * SEQL + 255) / 256, 256, 0, stream>>>(inputs, XB,   NOBS * SEQL);
  k_tanh2b<<<(NCTL * SEQL + 255) / 256, 256, 0, stream>>>(controls, UB, NCTL * SEQL);
  k_tr2b  <<<(NOBS * NLAT + 255) / 256, 256, 0, stream>>>(Wout, WoutT, NOBS, NLAT);

  // Stage 2: precompute GEMMs (G in fp32)
  gemm_bf16<<<dim3(NLAT / 64, NLAT / 64), 256, 0, stream>>>(WoutT, WoutB, Gf, nullptr,
                                                            NLAT, NLAT, NOBS);
  gemm_bf16<<<dim3(SEQL / 64, NLAT / 64), 256, 0, stream>>>(WoutT, XB, nullptr, BmatB,
                                                            NLAT, SEQL, NOBS);
  gemm_bf16<<<dim3(SEQL / 64, NLAT / 64), 256, 0, stream>>>(WinB, UB, nullptr, CinB,
                                                            NLAT, SEQL, NCTL);

  // Stage 3: sequential scan (cooperative so all 256 blocks are co-resident)
  const float* Gc = Gf; const float* Wrc = Wr; const u16* Bc = BmatB; const u16* Cc = CinB;
  float* zsp = zs; u16* tdp = TD; u64* fzp = fzbuf;
  const int* it = itp; const float* lr = lrp;
  void* args[9] = { &Gc, &Wrc, &Bc, &Cc, &zsp, &tdp, &fzp, &it, &lr };
  hipLaunchCooperativeKernel((void*)scan_kernel, dim3(NLAT / 8), dim3(256), args, 0, stream);

  // Stage 4: pred_xs = Wout @ tanh(z_projs)
  gemm_bf16<<<dim3(SEQL / 64, NOBS / 64), 256, 0, stream>>>(WoutB, TD, pred, nullptr,
                                                            NOBS, SEQL, NLAT);
}

// Round 5
// 200910.840 us; speedup vs baseline: 11.0613x; 1.0269x over previous
//
#include <hip/hip_runtime.h>
#include <hip/hip_bf16.h>

// NeuralKalmanFilter scan: 4096 steps x 20 inference iters = 81920 sequential phases.
// Per phase: one 2048x2048 matvec (G = Wout^T Wout, precomputed) + z update + all-to-all
// broadcast of the 2048-vector fz across 256 blocks (1/CU).
// R5: register-resident bf16 weights. R3/R4's fp32 float4 weight arrays (128 regs) were
// NOT kept in VGPRs (VGPR_Count=100) -> compiler streamed ~128KB/block/phase of weights
// from scratch/L2, ~930ns/phase of L2 BW per XCD — the dominant phase term. Pack G and Wr
// rows as bf16 pairs in uint2[16] (32 VGPRs each, the R2 recipe that provably stayed
// resident at VGPR=128), unpack with shl/and at use. G built directly in bf16 (R1 showed
// identical absmax). Keeps R4's replicated fence-free tag-in-data sync + R3 coalesced poll.

#define SEQL 4096
#define NLAT 2048
#define NOBS 1024
#define NCTL 512

typedef unsigned short u16;
typedef unsigned int   u32;
typedef unsigned long long u64;
typedef float v2f __attribute__((ext_vector_type(2)));

__device__ __forceinline__ float bfl(u32 u)  { return __uint_as_float(u << 16); }
__device__ __forceinline__ float bfh(u32 u)  { return __uint_as_float(u & 0xffff0000u); }
__device__ __forceinline__ float bf2f(u16 s) { return __uint_as_float(((u32)s) << 16); }
__device__ __forceinline__ u16 f2bf(float f) {            // round-to-nearest-even bf16
  u32 x = __float_as_uint(f);
  return (u16)((x + 0x7fffu + ((x >> 16) & 1u)) >> 16);
}

#if __has_builtin(__builtin_elementwise_fma)
__device__ __forceinline__ v2f pkfma(v2f a, v2f b, v2f c) {
  return __builtin_elementwise_fma(a, b, c);
}
#else
__device__ __forceinline__ v2f pkfma(v2f a, v2f b, v2f c) {
  v2f r; r.x = fmaf(a.x, b.x, c.x); r.y = fmaf(a.y, b.y, c.y); return r;
}
#endif

// Branch-free tanh: tanh(x) = 1 - 2/(exp2(2*log2e*x)+1). Saturates naturally at +-1.
__device__ __forceinline__ float fast_tanh(float x) {
#if __has_builtin(__builtin_amdgcn_exp2f) && __has_builtin(__builtin_amdgcn_rcpf)
  float e = __builtin_amdgcn_exp2f(x * 2.8853900817779268f);
  return 1.f - 2.f * __builtin_amdgcn_rcpf(e + 1.f);
#else
  return tanhf(x);
#endif
}

// ---------------- elementwise converts ----------------
__global__ void k_f2b(const float* __restrict__ in, u16* __restrict__ out, int n) {
  int i = blockIdx.x * 256 + threadIdx.x;
  if (i < n) out[i] = f2bf(in[i]);
}
__global__ void k_tanh2b(const float* __restrict__ in, u16* __restrict__ out, int n) {
  int i = blockIdx.x * 256 + threadIdx.x;
  if (i < n) out[i] = f2bf(tanhf(in[i]));
}
// out[c*R + r] = bf16(in[r*C + c])   (build Wout^T)
__global__ void k_tr2b(const float* __restrict__ in, u16* __restrict__ out, int R, int C) {
  int i = blockIdx.x * 256 + threadIdx.x;
  if (i < R * C) {
    int r = i / C, c = i % C;
    out[(size_t)c * R + r] = f2bf(in[i]);
  }
}

// ---------------- simple LDS-tiled bf16 GEMM (fp32 acc), 64x64 tile ----------------
__global__ __launch_bounds__(256) void gemm_bf16(
    const u16* __restrict__ A, const u16* __restrict__ B,
    float* __restrict__ Cf, u16* __restrict__ Cb, int M, int N, int K)
{
  __shared__ float As[32][68];
  __shared__ float Bs[32][68];
  const int tid = threadIdx.x;
  const int colBase = blockIdx.x * 64, rowBase = blockIdx.y * 64;
  const int tx = tid & 15, ty = tid >> 4;
  const int ar = tid >> 2, ak = (tid & 3) * 8;
  const int bk = tid >> 3, bc = (tid & 7) * 8;
  const u16* Ap = A + (size_t)(rowBase + ar) * K + ak;
  const u16* Bp = B + (size_t)bk * N + colBase + bc;
  float acc[4][4] = {};

  for (int k0 = 0; k0 < K; k0 += 32) {
    uint4 a = *(const uint4*)(Ap + k0);
    uint4 b = *(const uint4*)(Bp + (size_t)k0 * N);
    As[ak + 0][ar] = bfl(a.x); As[ak + 1][ar] = bfh(a.x);
    As[ak + 2][ar] = bfl(a.y); As[ak + 3][ar] = bfh(a.y);
    As[ak + 4][ar] = bfl(a.z); As[ak + 5][ar] = bfh(a.z);
    As[ak + 6][ar] = bfl(a.w); As[ak + 7][ar] = bfh(a.w);
    Bs[bk][bc + 0] = bfl(b.x); Bs[bk][bc + 1] = bfh(b.x);
    Bs[bk][bc + 2] = bfl(b.y); Bs[bk][bc + 3] = bfh(b.y);
    Bs[bk][bc + 4] = bfl(b.z); Bs[bk][bc + 5] = bfh(b.z);
    Bs[bk][bc + 6] = bfl(b.w); Bs[bk][bc + 7] = bfh(b.w);
    __syncthreads();
#pragma unroll
    for (int kk = 0; kk < 32; kk++) {
      float4 av = *(const float4*)&As[kk][ty * 4];
      float4 bv = *(const float4*)&Bs[kk][tx * 4];
      float a4[4] = {av.x, av.y, av.z, av.w};
      float b4[4] = {bv.x, bv.y, bv.z, bv.w};
#pragma unroll
      for (int i = 0; i < 4; i++)
#pragma unroll
        for (int q = 0; q < 4; q++)
          acc[i][q] = fmaf(a4[i], b4[q], acc[i][q]);
    }
    __syncthreads();
  }

  if (Cf) {
#pragma unroll
    for (int i = 0; i < 4; i++) {
      float4 v = make_float4(acc[i][0], acc[i][1], acc[i][2], acc[i][3]);
      *(float4*)&Cf[(size_t)(rowBase + ty * 4 + i) * N + colBase + tx * 4] = v;
    }
  } else {
#pragma unroll
    for (int i = 0; i < 4; i++) {
      u64 pk = (u64)f2bf(acc[i][0]) | ((u64)f2bf(acc[i][1]) << 16) |
               ((u64)f2bf(acc[i][2]) << 32) | ((u64)f2bf(acc[i][3]) << 48);
      *(u64*)&Cb[(size_t)(rowBase + ty * 4 + i) * N + colBase + tx * 4] = pk;
    }
  }
}

// ---------------- the sequential scan (cooperative, 256 blocks x 256 threads) ----------
__global__ void __launch_bounds__(256, 1)
scan_kernel(const u16* __restrict__ G,      // 2048x2048 bf16 (Wout^T Wout)
            const u16* __restrict__ Wr,     // 2048x2048 bf16
            const u16* __restrict__ Bmat,   // 2048x4096 bf16 (Wout^T @ inputs)
            const u16* __restrict__ Cin,    // 2048x4096 bf16 (Win @ tanh(controls))
            float* __restrict__ zs,         // 2048x4096 f32 out
            u16* __restrict__ td,           // 2048x4096 bf16 out: tanh(drive)
            u64* __restrict__ fzbuf,        // 2 parities x 8 replicas x 768 words
            const int* __restrict__ itp, const float* __restrict__ lrp)
{
  __shared__ __align__(16) float fzLDS[NLAT];   // current fz, fp32
  __shared__ float corrLDS[8], wrLDS[8];
  __shared__ int sAbort;

  const int tid = threadIdx.x, bid = blockIdx.x;
  const int lane = tid & 63, wave = tid >> 6;
  const int row_local = wave * 2 + (lane >> 5);    // 0..7
  const int chunk = lane & 31;                     // 0..31
  const int row = bid * 8 + row_local;
  const int row8 = bid * 8 + lane;                 // valid for lane < 8

  const int niters = *itp;       // 20
  const float lr = *lrp;         // 0.05

#if __has_builtin(__builtin_amdgcn_s_setprio)
  if (wave == 0) __builtin_amdgcn_s_setprio(1);    // publisher wave wins issue arbitration
#endif

  // Per-thread weight slice, REGISTER-RESIDENT packed bf16 (uint2 = 4 columns):
  // columns chunk*4 + 128*i + (0..3), i = 0..15. 32 VGPRs per matrix.
  uint2 wGp[16], wWp[16];
  {
    const u16* gRow = G  + (size_t)row * NLAT + chunk * 4;
    const u16* wRow = Wr + (size_t)row * NLAT + chunk * 4;
#pragma unroll
    for (int i = 0; i < 16; i++) {
      wGp[i] = *(const uint2*)(gRow + 128 * i);
      wWp[i] = *(const uint2*)(wRow + 128 * i);
    }
  }
  for (int i = tid; i < NLAT; i += 256) fzLDS[i] = 0.f;   // z0 = 0 -> fz = 0
  if (tid == 0) sAbort = 0;

  // Hoisted unpack mapping for the 3 words this thread polls: w = tid, tid+256, tid+512.
  // Word w covers rows (w/3)*8 + (w%3)*3 .. +2 (slot 2 holds only 2 valid values).
  const int w0 = tid, w1 = tid + 256, w2 = tid + 512;
  float* o0; float* o1; float* o2; int s0_, s1_, s2_;
  {
    int b0 = w0 / 3; s0_ = w0 - b0 * 3; o0 = fzLDS + b0 * 8 + s0_ * 3;
    int b1 = w1 / 3; s1_ = w1 - b1 * 3; o1 = fzLDS + b1 * 8 + s1_ * 3;
    int b2 = w2 / 3; s2_ = w2 - b2 * 3; o2 = fzLDS + b2 * 8 + s2_ * 3;
  }

  float z = 0.f, fz = 0.f, drive = 0.f, bv = 0.f;   // live in lanes<8 of wave 0
  float bvN = 0.f, cvN = 0.f;
  if (wave == 0 && lane < 8) {                      // prefetch step-0 columns
    bvN = bf2f(Bmat[(size_t)row8 * SEQL]);
    cvN = bf2f(Cin [(size_t)row8 * SEQL]);
  }
  __syncthreads();

  u32 p = 0;
  for (int t = 0; t < SEQL; t++) {
    for (int j = 0; j < niters; j++) {
      p++;
      // ---- matvec on fzLDS (fz after phase p-1), bf16 weights unpacked in-register ----
      v2f aG = {0.f, 0.f}, aW = {0.f, 0.f};
      const float4* f4 = (const float4*)(fzLDS + chunk * 4);
      if (j == 0) {
#pragma unroll
        for (int i = 0; i < 16; i++) {
          float4 v = f4[32 * i];
          uint2 g = wGp[i], w = wWp[i];
          v2f vlo = {v.x, v.y}, vhi = {v.z, v.w};
          aG = pkfma((v2f){bfl(g.x), bfh(g.x)}, vlo, aG);
          aG = pkfma((v2f){bfl(g.y), bfh(g.y)}, vhi, aG);
          aW = pkfma((v2f){bfl(w.x), bfh(w.x)}, vlo, aW);
          aW = pkfma((v2f){bfl(w.y), bfh(w.y)}, vhi, aW);
        }
      } else {
#pragma unroll
        for (int i = 0; i < 16; i++) {
          float4 v = f4[32 * i];
          uint2 g = wGp[i];
          aG = pkfma((v2f){bfl(g.x), bfh(g.x)}, (v2f){v.x, v.y}, aG);
          aG = pkfma((v2f){bfl(g.y), bfh(g.y)}, (v2f){v.z, v.w}, aG);
        }
      }
      float accG = aG.x + aG.y, accW = aW.x + aW.y;
#pragma unroll
      for (int m = 16; m; m >>= 1) accG += __shfl_xor(accG, m, 64);
      if (j == 0) {
#pragma unroll
        for (int m = 16; m; m >>= 1) accW += __shfl_xor(accW, m, 64);
      }
      if (chunk == 0) {
        corrLDS[row_local] = accG;
        if (j == 0) wrLDS[row_local] = accW;
      }
      __syncthreads();   // corrLDS ready; all matvec reads of fzLDS done

      // ---- wave 0: z-update + publish to 8 replicas; waves 1-3 fall through to poll ----
      if (wave == 0) {
        u32 myfz = 0;
        if (lane < 8) {
          if (j == 0) { bv = bvN; drive = wrLDS[lane] + cvN; }
          float corr = bv - corrLDS[lane];              // (Wout^T(x - Wout fz))[row]
          float dz = (z - drive) - (1.f - fz * fz) * corr;
          z -= lr * dz;
          fz = fast_tanh(z);
          myfz = f2bf(fz);
        }
        // pack 3 values per word via shuffles; lanes<24 write replica lane/3, slot lane%3
        int slot = lane % 3;
        u32 a = __shfl((int)myfz, 3 * slot, 64);
        u32 b = __shfl((int)myfz, 3 * slot + 1, 64);
        u32 c = __shfl((int)myfz, 3 * slot + 2, 64);
        if (lane < 24) {
          int rep = lane / 3;
          u64 word = (u64)(u16)p | ((u64)a << 16) | ((u64)b << 32) | ((u64)c << 48);
          __hip_atomic_store(
              &fzbuf[((size_t)(p & 1) * 8 + rep) * 768 + bid * 3 + slot], word,
              __ATOMIC_RELAXED, __HIP_MEMORY_SCOPE_AGENT);
        }
        if (lane < 8) {                 // off the publish critical path
          if (j == 0) {
            td[(size_t)row8 * SEQL + t] = f2bf(fast_tanh(drive));
            int tn = t + 1 < SEQL ? t + 1 : t;
            bvN = bf2f(Bmat[(size_t)row8 * SEQL + tn]);
            cvN = bf2f(Cin [(size_t)row8 * SEQL + tn]);
          }
          if (j == niters - 1) zs[(size_t)row8 * SEQL + t] = z;
        }
      }

      // ---- poll own replica (bid&7): thread tid reads words tid, tid+256, tid+512 ----
      const u64* base = fzbuf + ((size_t)(p & 1) * 8 + (bid & 7)) * 768;
      u16 want = (u16)p;
      u64 g0 = __hip_atomic_load(base + w0, __ATOMIC_RELAXED, __HIP_MEMORY_SCOPE_AGENT);
      u64 g1 = __hip_atomic_load(base + w1, __ATOMIC_RELAXED, __HIP_MEMORY_SCOPE_AGENT);
      u64 g2 = __hip_atomic_load(base + w2, __ATOMIC_RELAXED, __HIP_MEMORY_SCOPE_AGENT);
      int guard = 0;
      while ((u16)g0 != want || (u16)g1 != want || (u16)g2 != want) {
        if (++guard > 2000000) { sAbort = 1; break; }
#if __has_builtin(__builtin_amdgcn_s_sleep)
        __builtin_amdgcn_s_sleep(1);    // ~64cy backoff: fewer redundant in-flight reads
#endif
        if ((u16)g0 != want)
          g0 = __hip_atomic_load(base + w0, __ATOMIC_RELAXED, __HIP_MEMORY_SCOPE_AGENT);
        if ((u16)g1 != want)
          g1 = __hip_atomic_load(base + w1, __ATOMIC_RELAXED, __HIP_MEMORY_SCOPE_AGENT);
        if ((u16)g2 != want)
          g2 = __hip_atomic_load(base + w2, __ATOMIC_RELAXED, __HIP_MEMORY_SCOPE_AGENT);
      }

      // ---- unpack straight into fzLDS (slot-2 words carry only 2 valid values) ----
      o0[0] = bf2f((u16)(g0 >> 16)); o0[1] = bf2f((u16)(g0 >> 32));
      if (s0_ != 2) o0[2] = bf2f((u16)(g0 >> 48));
      o1[0] = bf2f((u16)(g1 >> 16)); o1[1] = bf2f((u16)(g1 >> 32));
      if (s1_ != 2) o1[2] = bf2f((u16)(g1 >> 48));
      o2[0] = bf2f((u16)(g2 >> 16)); o2[1] = bf2f((u16)(g2 >> 32));
      if (s2_ != 2) o2[2] = bf2f((u16)(g2 >> 48));
      __syncthreads();   // fzLDS ready for next phase
      if (sAbort) return;
    }
  }
}

// ---------------- host ----------------
extern "C" void kernel_launch(void* const* d_in, const int* in_sizes, int n_in,
                              void* d_out, int out_size, void* d_ws, size_t ws_size,
                              hipStream_t stream)
{
  const float* inputs   = (const float*)d_in[0];   // (1024, 4096)
  const float* controls = (const float*)d_in[1];   // (512, 4096)
  const float* Wr       = (const float*)d_in[2];   // (2048, 2048)
  const float* Win      = (const float*)d_in[3];   // (2048, 512)
  const float* Wout     = (const float*)d_in[4];   // (1024, 2048)
  const int*   itp      = (const int*)d_in[5];     // 20
  const float* lrp      = (const float*)d_in[6];   // 0.05
  float* out = (float*)d_out;
  char* ws = (char*)d_ws;

  size_t off = 0;
  u16*   WrB   = (u16*)(ws + off);   off += (size_t)NLAT * NLAT * 2;  // 8 MB
  u16*   Gb    = (u16*)(ws + off);   off += (size_t)NLAT * NLAT * 2;  // 8 MB
  u16*   WoutB = (u16*)(ws + off);   off += (size_t)NOBS * NLAT * 2;  // 4 MB
  u16*   WinB  = (u16*)(ws + off);   off += (size_t)NLAT * NCTL * 2;  // 2 MB
  u16*   XB    = (u16*)(ws + off);   off += (size_t)NOBS * SEQL * 2;  // 8 MB
  u16*   UB    = (u16*)(ws + off);   off += (size_t)NCTL * SEQL * 2;  // 4 MB
  u16*   WoutT = (u16*)(ws + off);   off += (size_t)NLAT * NOBS * 2;  // 4 MB
  u16*   CinB  = (u16*)(ws + off);   off += (size_t)NLAT * SEQL * 2;  // 16 MB
  u16*   TD    = (u16*)(ws + off);   off += (size_t)NLAT * SEQL * 2;  // 16 MB
  u64*   fzbuf = (u64*)(ws + off);   off += (size_t)2 * 8 * 768 * 8;  // 96 KB

  float* zs   = out;                        // (2048, 4096) f32
  float* pred = out + (size_t)NLAT * SEQL;  // (1024, 4096) f32
  u16* BmatB  = (u16*)pred;  // B = Wout^T @ inputs (bf16, 16MB) overlays pred region;
                             // consumed by scan, then overwritten by the final GEMM.

  // Stage 1: converts / transpose
  k_f2b   <<<(NLAT * NLAT + 255) / 256, 256, 0, stream>>>(Wr,    WrB,   NLAT * NLAT);
  k_f2b   <<<(NOBS * NLAT + 255) / 256, 256, 0, stream>>>(Wout,  WoutB, NOBS * NLAT);
  k_f2b   <<<(NLAT * NCTL + 255) / 256, 256, 0, stream>>>(Win,   WinB,  NLAT * NCTL);
  k_f2b   <<<(NOBS * SEQL + 255) / 256, 256, 0, stream>>>(inputs, XB,   NOBS * SEQL);
  k_tanh2b<<<(NCTL * SEQL + 255) / 256, 256, 0, stream>>>(controls, UB, NCTL * SEQL);
  k_tr2b  <<<(NOBS * NLAT + 255) / 256, 256, 0, stream>>>(Wout, WoutT, NOBS, NLAT);

  // Stage 2: precompute GEMMs (G directly in bf16)
  gemm_bf16<<<dim3(NLAT / 64, NLAT / 64), 256, 0, stream>>>(WoutT, WoutB, nullptr, Gb,
                                                            NLAT, NLAT, NOBS);
  gemm_bf16<<<dim3(SEQL / 64, NLAT / 64), 256, 0, stream>>>(WoutT, XB, nullptr, BmatB,
                                                            NLAT, SEQL, NOBS);
  gemm_bf16<<<dim3(SEQL / 64, NLAT / 64), 256, 0, stream>>>(WinB, UB, nullptr, CinB,
                                                            NLAT, SEQL, NCTL);

  // Stage 3: sequential scan (cooperative so all 256 blocks are co-resident)
  const u16* Gc = Gb; const u16* Wrc = WrB; const u16* Bc = BmatB; const u16* Cc = CinB;
  float* zsp = zs; u16* tdp = TD; u64* fzp = fzbuf;
  const int* it = itp; const float* lr = lrp;
  void* args[9] = { &Gc, &Wrc, &Bc, &Cc, &zsp, &tdp, &fzp, &it, &lr };
  hipLaunchCooperativeKernel((void*)scan_kernel, dim3(NLAT / 8), dim3(256), args, 0, stream);

  // Stage 4: pred_xs = Wout @ tanh(z_projs)
  gemm_bf16<<<dim3(SEQL / 64, NOBS / 64), 256, 0, stream>>>(WoutB, TD, pred, nullptr,
                                                            NOBS, SEQL, NLAT);
}